// Round 14
// baseline (42.982 us; speedup 1.0000x reference)
//
#include <hip/hip_runtime.h>

#define NE 19
#define CIN 64
#define Z1T_STRIDE 80          // bytes per Z1T row (32 bf16 of 40); 16B-aligned, 2-way banks = free
#define SLICE 5120             // per-graph slice: Z1T (64*80), then reused as f32 out-bounce (4864 B)

typedef float f32x4 __attribute__((ext_vector_type(4)));
typedef unsigned short u16x4 __attribute__((ext_vector_type(4)));
typedef unsigned short u16x8 __attribute__((ext_vector_type(8)));
typedef __bf16 bf16x8 __attribute__((ext_vector_type(8)));

__device__ __forceinline__ unsigned short f2bf(float f) {
  unsigned u = __builtin_bit_cast(unsigned, f);
  return (unsigned short)((u + 0x7FFFu + ((u >> 16) & 1u)) >> 16);
}
__device__ __forceinline__ int swz(int row, int byteoff) {
  return row * 256 + (byteoff ^ ((row & 7) << 4));
}
__device__ __forceinline__ u16x8 packW(const float* q) {
  f32x4 a = *(const f32x4*)q;
  f32x4 b = *(const f32x4*)(q + 4);
  u16x8 h;
  h[0]=f2bf(a[0]); h[1]=f2bf(a[1]); h[2]=f2bf(a[2]); h[3]=f2bf(a[3]);
  h[4]=f2bf(b[0]); h[5]=f2bf(b[1]); h[6]=f2bf(b[2]); h[7]=f2bf(b[3]);
  return h;
}

// Single fused kernel: 2 graphs/wave, zero barriers, all compute in MFMA.
// Each wave builds its W/A fragments from global (L2-hot). No prep dispatch.
// launch_bounds (128,2): VGPR cap 128. Do NOT raise min-waves: (128,4) clamps
// to 64 VGPR and spills (R12: FETCH +20MB, WRITE 2x, dur 48us). LDS-bound
// occupancy (8 blocks/CU = 4 waves/SIMD) is unchanged by the 128 cap.
__global__ __launch_bounds__(128, 2) void gconv_kernel(
    const float* __restrict__ x, const float* __restrict__ ew,
    const float* __restrict__ Wrel, const float* __restrict__ Wroot,
    const float* __restrict__ bias, float* __restrict__ out)
{
  __shared__ __align__(16) unsigned char sl[4 * SLICE];  // 20480 B -> 8 blocks/CU

  const int t = threadIdx.x;
  const int lane = t & 63;
  const int wv = t >> 6;
  const int g0 = blockIdx.x * 4 + wv * 2;   // wave owns graphs g0, g0+1
  const int lr = lane & 15, hg = lane >> 4;
  unsigned char* slice[2] = { sl + (wv * 2) * SLICE, sl + (wv * 2 + 1) * SLICE };

  // ---- X A-frags for BOTH graphs FIRST: 16 independent HBM loads issued up
  // front; frag-building VALU below hides under their latency.
  u16x8 af[2][2][2];   // [graph][mt][kt]
  #pragma unroll
  for (int gi = 0; gi < 2; ++gi) {
    const float* xg = x + (long long)(g0 + gi) * NE * CIN;
    #pragma unroll
    for (int mt = 0; mt < 2; ++mt) {
      int rr = mt * 16 + lr; if (rr > NE - 1) rr = NE - 1;  // dup rows, writes guarded
      const float* xr = xg + rr * CIN + hg * 8;
      #pragma unroll
      for (int kt = 0; kt < 2; ++kt) af[gi][mt][kt] = packW(xr + kt * 32);
    }
  }

  // ---- A-mix A-frags from ew (softplus on the fly; 16 L2-hot scalar loads).
  // afm[mt]: lane holds A[mt*16+lr][k=hg*8+b], A[i][j] = sp(ew[j*19+i]).
  u16x8 afm[2];
  #pragma unroll
  for (int mt = 0; mt < 2; ++mt) {
    int row = mt * 16 + lr;
    u16x8 h;
    #pragma unroll
    for (int b = 0; b < 8; ++b) {
      int k = hg * 8 + b;
      float v = 0.0f;
      if (row < NE && k < NE) {
        float z = ew[k * NE + row];
        v = fmaxf(z, 0.0f) + log1pf(expf(-fabsf(z)));
      }
      h[b] = f2bf(v);
    }
    afm[mt] = h;
  }
  float biasv[4];
  #pragma unroll
  for (int nt = 0; nt < 4; ++nt) biasv[nt] = bias[nt * 16 + lr];

  // ---- half 1: Z1 = X @ Wrel^T. B-frags built from global Wrel (L2-hot),
  // shared across both graphs.
  {
    u16x8 bf1[8];   // [kt*4+nt]
    #pragma unroll
    for (int i = 0; i < 8; ++i) {
      int kt = i >> 2, nt = i & 3;
      bf1[i] = packW(Wrel + (nt * 16 + lr) * CIN + kt * 32 + hg * 8);
    }
    #pragma unroll
    for (int gi = 0; gi < 2; ++gi) {
      f32x4 zacc[2][4];
      #pragma unroll
      for (int mt = 0; mt < 2; ++mt)
        #pragma unroll
        for (int nt = 0; nt < 4; ++nt) { zacc[mt][nt][0]=0.f; zacc[mt][nt][1]=0.f; zacc[mt][nt][2]=0.f; zacc[mt][nt][3]=0.f; }
      #pragma unroll
      for (int nt = 0; nt < 4; ++nt)
        #pragma unroll
        for (int mt = 0; mt < 2; ++mt) {
          zacc[mt][nt] = __builtin_amdgcn_mfma_f32_16x16x32_bf16(
              __builtin_bit_cast(bf16x8, af[gi][mt][0]), __builtin_bit_cast(bf16x8, bf1[nt]), zacc[mt][nt], 0, 0, 0);
          zacc[mt][nt] = __builtin_amdgcn_mfma_f32_16x16x32_bf16(
              __builtin_bit_cast(bf16x8, af[gi][mt][1]), __builtin_bit_cast(bf16x8, bf1[4 + nt]), zacc[mt][nt], 0, 0, 0);
        }
      // bounce Z1 -> Z1T[c][j] bf16 (j 19..31 zeroed), 8 ds_write_b64
      unsigned char* z1 = slice[gi];
      #pragma unroll
      for (int nt = 0; nt < 4; ++nt) {
        int c = nt * 16 + lr;
        u16x4 h0;
        #pragma unroll
        for (int b = 0; b < 4; ++b) h0[b] = f2bf(zacc[0][nt][b]);
        *(u16x4*)(z1 + c * Z1T_STRIDE + hg * 8) = h0;
        u16x4 h1;
        #pragma unroll
        for (int b = 0; b < 4; ++b) {
          int j = 16 + hg * 4 + b;
          h1[b] = (j < NE) ? f2bf(zacc[1][nt][b]) : (unsigned short)0;
        }
        *(u16x4*)(z1 + c * Z1T_STRIDE + 32 + hg * 8) = h1;
      }
    }
  }

  // ---- half 2 + mix + epilogue. B-frags from global Wroot (L2-hot).
  {
    u16x8 bf2[8];
    #pragma unroll
    for (int i = 0; i < 8; ++i) {
      int kt = i >> 2, nt = i & 3;
      bf2[i] = packW(Wroot + (nt * 16 + lr) * CIN + kt * 32 + hg * 8);
    }
    #pragma unroll
    for (int gi = 0; gi < 2; ++gi) {
      unsigned char* z1 = slice[gi];
      f32x4 acc[2][4];
      #pragma unroll
      for (int mt = 0; mt < 2; ++mt)
        #pragma unroll
        for (int nt = 0; nt < 4; ++nt) { acc[mt][nt][0]=0.f; acc[mt][nt][1]=0.f; acc[mt][nt][2]=0.f; acc[mt][nt][3]=0.f; }
      #pragma unroll
      for (int nt = 0; nt < 4; ++nt)
        #pragma unroll
        for (int mt = 0; mt < 2; ++mt) {
          acc[mt][nt] = __builtin_amdgcn_mfma_f32_16x16x32_bf16(
              __builtin_bit_cast(bf16x8, af[gi][mt][0]), __builtin_bit_cast(bf16x8, bf2[nt]), acc[mt][nt], 0, 0, 0);
          acc[mt][nt] = __builtin_amdgcn_mfma_f32_16x16x32_bf16(
              __builtin_bit_cast(bf16x8, af[gi][mt][1]), __builtin_bit_cast(bf16x8, bf2[4 + nt]), acc[mt][nt], 0, 0, 0);
        }
      // mix as MFMA: acc += A @ Z1
      #pragma unroll
      for (int nt = 0; nt < 4; ++nt) {
        u16x8 zf = *(const u16x8*)(z1 + (nt * 16 + lr) * Z1T_STRIDE + hg * 16);
        acc[0][nt] = __builtin_amdgcn_mfma_f32_16x16x32_bf16(
            __builtin_bit_cast(bf16x8, afm[0]), __builtin_bit_cast(bf16x8, zf), acc[0][nt], 0, 0, 0);
        acc[1][nt] = __builtin_amdgcn_mfma_f32_16x16x32_bf16(
            __builtin_bit_cast(bf16x8, afm[1]), __builtin_bit_cast(bf16x8, zf), acc[1][nt], 0, 0, 0);
      }
      // bias + f32 out-bounce OVERLAID on this graph's slice (all zf reads
      // precede these writes in same-wave program order -> race-free)
      #pragma unroll
      for (int mt = 0; mt < 2; ++mt)
        #pragma unroll
        for (int nt = 0; nt < 4; ++nt)
          #pragma unroll
          for (int b = 0; b < 4; ++b) {
            int row = mt * 16 + hg * 4 + b;
            if (row < NE)
              *(float*)(&z1[swz(row, (nt * 16 + lr) * 4)]) = acc[mt][nt][b] + biasv[nt];
          }
      // coalesced epilogue: 1KB contiguous per wave instruction
      const long long orow0 = (long long)(g0 + gi) * NE;
      #pragma unroll
      for (int p = 0; p < 5; ++p) {
        int q = p * 64 + lane;
        if (q < NE * 16) {
          int r = q >> 4, c = q & 15;
          f32x4 v = *(const f32x4*)(&z1[swz(r, c * 16)]);
          *(f32x4*)(out + (orow0 + r) * CIN + c * 4) = v;
        }
      }
    }
  }
}

extern "C" void kernel_launch(void* const* d_in, const int* in_sizes, int n_in,
                              void* d_out, int out_size, void* d_ws, size_t ws_size,
                              hipStream_t stream) {
  const float* x    = (const float*)d_in[0];
  const float* ew   = (const float*)d_in[1];
  const float* Wrel = (const float*)d_in[2];
  const float* Wroot= (const float*)d_in[3];
  const float* bias = (const float*)d_in[4];
  float* out = (float*)d_out;

  const int ngraphs = (in_sizes[0] / CIN) / NE;   // 8192
  const int nblocks = ngraphs / 4;                // 2048 blocks, 2 graphs/wave
  gconv_kernel<<<nblocks, 128, 0, stream>>>(x, ew, Wrel, Wroot, bias, out);
}

// Round 15
// 26.113 us; speedup vs baseline: 1.6460x; 1.6460x over previous
//
#include <hip/hip_runtime.h>

#define NE 19
#define CIN 64
#define Z1T_STRIDE 80          // bytes per Z1T row (32 bf16 of 40); 16B-aligned, 2-way banks = free
#define SLICE 5120             // per-graph slice: Z1T (64*80), reused as f32 out-bounce (4864 B)
#define WS_AFRAG 16384         // ws: [0,16K) Wc B-frags; [16K,18K) A-mix A-frags

typedef float f32x4 __attribute__((ext_vector_type(4)));
typedef unsigned short u16x4 __attribute__((ext_vector_type(4)));
typedef unsigned short u16x8 __attribute__((ext_vector_type(8)));
typedef __bf16 bf16x8 __attribute__((ext_vector_type(8)));

__device__ __forceinline__ unsigned short f2bf(float f) {
  unsigned u = __builtin_bit_cast(unsigned, f);
  return (unsigned short)((u + 0x7FFFu + ((u >> 16) & 1u)) >> 16);
}
__device__ __forceinline__ int swz(int row, int byteoff) {
  return row * 256 + (byteoff ^ ((row & 7) << 4));
}
__device__ __forceinline__ u16x8 packW(const float* q) {
  f32x4 a = *(const f32x4*)q;
  f32x4 b = *(const f32x4*)(q + 4);
  u16x8 h;
  h[0]=f2bf(a[0]); h[1]=f2bf(a[1]); h[2]=f2bf(a[2]); h[3]=f2bf(a[3]);
  h[4]=f2bf(b[0]); h[5]=f2bf(b[1]); h[6]=f2bf(b[2]); h[7]=f2bf(b[3]);
  return h;
}

// K1 (5 blocks): pack Wc B-frags + softplus(A) A-frags (bf16) into workspace.
// B-frag fid = ((p*2+kt)*4+nt)*64+lane, p0=Wrel p1=Wroot.
__global__ void prep_kernel(const float* __restrict__ ew,
                            const float* __restrict__ Wrel,
                            const float* __restrict__ Wroot,
                            unsigned char* __restrict__ ws) {
  const int t = threadIdx.x, bid = blockIdx.x;
  if (bid < 4) {
    int fid = bid * 256 + t;
    int p = fid >> 9, kt = (fid >> 8) & 1, nt = (fid >> 6) & 3, lane = fid & 63;
    const float* Wsrc = p ? Wroot : Wrel;
    const float* q = Wsrc + (nt * 16 + (lane & 15)) * CIN + kt * 32 + (lane >> 4) * 8;
    u16x8 h;
    #pragma unroll
    for (int b = 0; b < 8; ++b) h[b] = f2bf(q[b]);
    *(u16x8*)(ws + fid * 16) = h;
  } else if (t < 128) {
    int mt = t >> 6, lane = t & 63;
    int row = mt * 16 + (lane & 15);
    u16x8 h;
    #pragma unroll
    for (int b = 0; b < 8; ++b) {
      int k = (lane >> 4) * 8 + b;
      float v = 0.0f;
      if (row < NE && k < NE) {
        float z = ew[k * NE + row];
        v = fmaxf(z, 0.0f) + log1pf(expf(-fabsf(z)));
      }
      h[b] = f2bf(v);
    }
    *(u16x8*)(ws + WS_AFRAG + t * 16) = h;
  }
}

// K2: single-wave blocks, 4 graphs per wave (sequential, lookahead-1 x
// prefetch), zero barriers, all compute in MFMA.
// out = A@(X@Wrel^T) + X@Wroot^T + bias
// launch_bounds (64,2): VGPR cap 128 (observed rule: cap = 256/min_waves).
// Do NOT raise min-waves — 64-VGPR clamp spills (R12: FETCH +20MB, WRITE 2x).
__global__ __launch_bounds__(64, 2) void gconv_kernel(
    const float* __restrict__ x, const float* __restrict__ bias,
    const unsigned char* __restrict__ ws, float* __restrict__ out)
{
  __shared__ __align__(16) unsigned char sl[2 * SLICE];  // 10240 B -> 16 blocks/CU

  const int lane = threadIdx.x & 63;
  const int g0 = blockIdx.x * 4;
  const int lr = lane & 15, hg = lane >> 4;
  const u16x8* fr = (const u16x8*)ws;

  const u16x8 afm0 = fr[1024 + lane];
  const u16x8 afm1 = fr[1088 + lane];
  float biasv[4];
  #pragma unroll
  for (int nt = 0; nt < 4; ++nt) biasv[nt] = bias[nt * 16 + lr];

  // Load one graph's X A-frags (8 x 16B contiguous loads, f32->bf16)
  auto LOADAF = [&](u16x8 af[2][2], int g) {
    const float* xg = x + (long long)g * NE * CIN;
    #pragma unroll
    for (int mt = 0; mt < 2; ++mt) {
      int rr = mt * 16 + lr; if (rr > NE - 1) rr = NE - 1;  // dup rows, writes guarded
      const float* xr = xg + rr * CIN + hg * 8;
      #pragma unroll
      for (int kt = 0; kt < 2; ++kt) af[mt][kt] = packW(xr + kt * 32);
    }
  };

  // Full per-graph pipeline: half1 -> Z1T -> half2 -> mix -> bounce -> store.
  // bf buffer reloaded per half (L2-hot) to bound live registers.
  auto PROC = [&](u16x8 af[2][2], unsigned char* z1, int g) {
    // half 1: Z1 = X @ Wrel^T
    u16x8 bf[8];
    #pragma unroll
    for (int i = 0; i < 8; ++i) bf[i] = fr[i * 64 + lane];
    f32x4 zacc[2][4];
    #pragma unroll
    for (int mt = 0; mt < 2; ++mt)
      #pragma unroll
      for (int nt = 0; nt < 4; ++nt) { zacc[mt][nt][0]=0.f; zacc[mt][nt][1]=0.f; zacc[mt][nt][2]=0.f; zacc[mt][nt][3]=0.f; }
    #pragma unroll
    for (int nt = 0; nt < 4; ++nt)
      #pragma unroll
      for (int mt = 0; mt < 2; ++mt) {
        zacc[mt][nt] = __builtin_amdgcn_mfma_f32_16x16x32_bf16(
            __builtin_bit_cast(bf16x8, af[mt][0]), __builtin_bit_cast(bf16x8, bf[nt]), zacc[mt][nt], 0, 0, 0);
        zacc[mt][nt] = __builtin_amdgcn_mfma_f32_16x16x32_bf16(
            __builtin_bit_cast(bf16x8, af[mt][1]), __builtin_bit_cast(bf16x8, bf[4 + nt]), zacc[mt][nt], 0, 0, 0);
      }
    // bounce Z1 -> Z1T[c][j] bf16 (j 19..31 zeroed), 8 ds_write_b64
    #pragma unroll
    for (int nt = 0; nt < 4; ++nt) {
      int c = nt * 16 + lr;
      u16x4 h0;
      #pragma unroll
      for (int b = 0; b < 4; ++b) h0[b] = f2bf(zacc[0][nt][b]);
      *(u16x4*)(z1 + c * Z1T_STRIDE + hg * 8) = h0;
      u16x4 h1;
      #pragma unroll
      for (int b = 0; b < 4; ++b) {
        int j = 16 + hg * 4 + b;
        h1[b] = (j < NE) ? f2bf(zacc[1][nt][b]) : (unsigned short)0;
      }
      *(u16x4*)(z1 + c * Z1T_STRIDE + 32 + hg * 8) = h1;
    }

    // half 2: acc = X @ Wroot^T
    #pragma unroll
    for (int i = 0; i < 8; ++i) bf[i] = fr[(8 + i) * 64 + lane];
    f32x4 acc[2][4];
    #pragma unroll
    for (int mt = 0; mt < 2; ++mt)
      #pragma unroll
      for (int nt = 0; nt < 4; ++nt) { acc[mt][nt][0]=0.f; acc[mt][nt][1]=0.f; acc[mt][nt][2]=0.f; acc[mt][nt][3]=0.f; }
    #pragma unroll
    for (int nt = 0; nt < 4; ++nt)
      #pragma unroll
      for (int mt = 0; mt < 2; ++mt) {
        acc[mt][nt] = __builtin_amdgcn_mfma_f32_16x16x32_bf16(
            __builtin_bit_cast(bf16x8, af[mt][0]), __builtin_bit_cast(bf16x8, bf[nt]), acc[mt][nt], 0, 0, 0);
        acc[mt][nt] = __builtin_amdgcn_mfma_f32_16x16x32_bf16(
            __builtin_bit_cast(bf16x8, af[mt][1]), __builtin_bit_cast(bf16x8, bf[4 + nt]), acc[mt][nt], 0, 0, 0);
      }
    // mix as MFMA: acc += A @ Z1
    #pragma unroll
    for (int nt = 0; nt < 4; ++nt) {
      u16x8 zf = *(const u16x8*)(z1 + (nt * 16 + lr) * Z1T_STRIDE + hg * 16);
      acc[0][nt] = __builtin_amdgcn_mfma_f32_16x16x32_bf16(
          __builtin_bit_cast(bf16x8, afm0), __builtin_bit_cast(bf16x8, zf), acc[0][nt], 0, 0, 0);
      acc[1][nt] = __builtin_amdgcn_mfma_f32_16x16x32_bf16(
          __builtin_bit_cast(bf16x8, afm1), __builtin_bit_cast(bf16x8, zf), acc[1][nt], 0, 0, 0);
    }
    // bias + f32 out-bounce overlaid on the slice (zf reads precede these
    // writes in same-wave program order -> race-free)
    #pragma unroll
    for (int mt = 0; mt < 2; ++mt)
      #pragma unroll
      for (int nt = 0; nt < 4; ++nt)
        #pragma unroll
        for (int b = 0; b < 4; ++b) {
          int row = mt * 16 + hg * 4 + b;
          if (row < NE)
            *(float*)(&z1[swz(row, (nt * 16 + lr) * 4)]) = acc[mt][nt][b] + biasv[nt];
        }
    // coalesced epilogue: 1KB contiguous per wave instruction
    const long long orow0 = (long long)g * NE;
    #pragma unroll
    for (int p = 0; p < 5; ++p) {
      int q = p * 64 + lane;
      if (q < NE * 16) {
        int r = q >> 4, c = q & 15;
        f32x4 v = *(const f32x4*)(&z1[swz(r, c * 16)]);
        *(f32x4*)(out + (orow0 + r) * CIN + c * 4) = v;
      }
    }
  };

  // 4 graphs, lookahead-1 prefetch: next graph's x loads are issued before
  // (or during) the current graph's compute; slices alternate (same-wave
  // program order makes slice reuse race-free).
  u16x8 afa[2][2], afb[2][2];
  LOADAF(afa, g0);
  LOADAF(afb, g0 + 1);
  PROC(afa, sl,         g0);
  LOADAF(afa, g0 + 2);
  PROC(afb, sl + SLICE, g0 + 1);
  LOADAF(afb, g0 + 3);
  PROC(afa, sl,         g0 + 2);
  PROC(afb, sl + SLICE, g0 + 3);
}

extern "C" void kernel_launch(void* const* d_in, const int* in_sizes, int n_in,
                              void* d_out, int out_size, void* d_ws, size_t ws_size,
                              hipStream_t stream) {
  const float* x    = (const float*)d_in[0];
  const float* ew   = (const float*)d_in[1];
  const float* Wrel = (const float*)d_in[2];
  const float* Wroot= (const float*)d_in[3];
  const float* bias = (const float*)d_in[4];
  float* out = (float*)d_out;
  unsigned char* ws = (unsigned char*)d_ws;   // needs 18432 B

  prep_kernel<<<5, 256, 0, stream>>>(ew, Wrel, Wroot, ws);

  const int ngraphs = (in_sizes[0] / CIN) / NE;   // 8192
  const int nblocks = ngraphs / 4;                // 2048 single-wave blocks
  gconv_kernel<<<nblocks, 64, 0, stream>>>(x, bias, ws, out);
}